// Round 3
// baseline (277.170 us; speedup 1.0000x reference)
//
#include <hip/hip_runtime.h>
#include <hip/hip_bf16.h>
#include <math.h>

// B=2, C=128, T=5 (Tc=4 ctx), H=W=48, heads=64, PATCH=7 (pad 3), K=196.
#define BATCH 2
#define CCH 128
#define TT 5
#define TC 4
#define HH 48
#define WW 48
#define HWPIX 2304
#define NHEAD 64
#define PAD 3
#define XSTRIDE (TT*HWPIX)   // per-channel stride in x

// ---------------------------------------------------------------------------
// K1: projections -> TRANSPOSED (h-major) layouts:
//   q_t  [b][h][2304]
//   phi_t[b][t][h][2304],  g_t[b][t][h][2304]
// grid (9 pixtiles, 4 headgroups, 10 bt). t==0: theta (16 heads/thread).
// t>0: phi+g together (16+16 accs) sharing the x loads.
// Weights are wave-uniform -> scalar loads; x loads & stores pixel-coalesced.
// ---------------------------------------------------------------------------
__global__ __launch_bounds__(256) void proj_kernel(
    const float* __restrict__ x,
    const float* __restrict__ w_theta,
    const float* __restrict__ w_phi,
    const float* __restrict__ w_g,
    float* __restrict__ q_t,
    float* __restrict__ phi_t,
    float* __restrict__ g_t)
{
    const int bt = blockIdx.z;         // 0..9
    const int b  = bt / TT;
    const int t  = bt % TT;
    const int h0 = blockIdx.y * 16;
    const int pix = blockIdx.x * 256 + threadIdx.x;
    const float* xp = x + ((size_t)(b * CCH) * TT + t) * HWPIX + pix;

    if (t == 0) {
        const float* wp = w_theta + (size_t)h0 * CCH;
        float acc[16];
#pragma unroll
        for (int j = 0; j < 16; ++j) acc[j] = 0.f;
        for (int c = 0; c < CCH; c += 4) {
            const float xv0 = xp[(size_t)(c + 0) * XSTRIDE];
            const float xv1 = xp[(size_t)(c + 1) * XSTRIDE];
            const float xv2 = xp[(size_t)(c + 2) * XSTRIDE];
            const float xv3 = xp[(size_t)(c + 3) * XSTRIDE];
#pragma unroll
            for (int j = 0; j < 16; ++j) {
                acc[j] = fmaf(wp[j * CCH + c + 0], xv0, acc[j]);
                acc[j] = fmaf(wp[j * CCH + c + 1], xv1, acc[j]);
                acc[j] = fmaf(wp[j * CCH + c + 2], xv2, acc[j]);
                acc[j] = fmaf(wp[j * CCH + c + 3], xv3, acc[j]);
            }
        }
#pragma unroll
        for (int j = 0; j < 16; ++j)
            q_t[((size_t)(b * NHEAD) + h0 + j) * HWPIX + pix] = acc[j];
    } else {
        const float* wpp = w_phi + (size_t)h0 * CCH;
        const float* wgp = w_g   + (size_t)h0 * CCH;
        float ap[16], ag[16];
#pragma unroll
        for (int j = 0; j < 16; ++j) { ap[j] = 0.f; ag[j] = 0.f; }
        for (int c = 0; c < CCH; c += 2) {
            const float xv0 = xp[(size_t)(c + 0) * XSTRIDE];
            const float xv1 = xp[(size_t)(c + 1) * XSTRIDE];
#pragma unroll
            for (int j = 0; j < 16; ++j) {
                ap[j] = fmaf(wpp[j * CCH + c + 0], xv0, ap[j]);
                ap[j] = fmaf(wpp[j * CCH + c + 1], xv1, ap[j]);
                ag[j] = fmaf(wgp[j * CCH + c + 0], xv0, ag[j]);
                ag[j] = fmaf(wgp[j * CCH + c + 1], xv1, ag[j]);
            }
        }
        const size_t base = ((size_t)((b * TC + (t - 1)) * NHEAD) + h0) * HWPIX + pix;
#pragma unroll
        for (int j = 0; j < 16; ++j) {
            phi_t[base + (size_t)j * HWPIX] = ap[j];
            g_t  [base + (size_t)j * HWPIX] = ag[j];
        }
    }
}

// ---------------------------------------------------------------------------
// K2: attention, fully coalesced. Block = 16 pixels x 4 t-waves (256 thr).
// lane = h_quarter(2b) | p_sub(4b). All phi/g/q loads contiguous over p_sub.
// Logits & attention weights live in LDS; softmax cooperative; y reduced over
// t in LDS then stored coalesced to y_t[b][h][pix] (aliases q_t: a block only
// reads q for its own pixels, before writing y for those same pixels).
// ---------------------------------------------------------------------------
__global__ __launch_bounds__(256) void attn_kernel(
    const float* __restrict__ phi_t,
    const float* __restrict__ g_t,
    const float* q_t,        // no restrict: aliases y_t
    float*       y_t)
{
    __shared__ float ls[208][17];        // logits -> att weights (rows 196+ = -inf)
    __shared__ float y_lds[4][NHEAD][17];

    const int tid  = threadIdx.x;
    const int w    = tid >> 6;           // t index 0..3
    const int lane = tid & 63;
    const int hs   = lane >> 4;          // h quarter 0..3
    const int ps   = lane & 15;          // pixel sub-index 0..15
    const int b    = blockIdx.y;
    const int p0   = blockIdx.x * 16;
    const int gp   = p0 + ps;
    const int X    = gp / WW;
    const int Y    = gp % WW;

    // pad rows so softmax chunks are uniform (13 per thread)
    if (tid < 192) ls[196 + (tid >> 4)][tid & 15] = -INFINITY;

    // q fragment: this lane's 16 heads at its pixel (coalesced over ps)
    const float* qb = q_t + ((size_t)(b * NHEAD) + hs * 16) * HWPIX + gp;
    float qr[16];
#pragma unroll
    for (int i = 0; i < 16; ++i) qr[i] = qb[(size_t)i * HWPIX];

    // ---- phase 1: logits ----
    const float* pb = phi_t + ((size_t)((b * TC + w) * NHEAD) + hs * 16) * HWPIX;
#pragma unroll
    for (int i = 0; i < 7; ++i) {
        const int nx = min(max(X - PAD + i, 0), HH - 1);
#pragma unroll
        for (int j = 0; j < 7; ++j) {
            const int ny = min(max(Y - PAD + j, 0), WW - 1);
            const int kp = nx * WW + ny;
            float s = 0.f;
#pragma unroll
            for (int hh = 0; hh < 16; ++hh)
                s = fmaf(qr[hh], pb[(size_t)hh * HWPIX + kp], s);
            s += __shfl_xor(s, 16);      // reduce over the 4 h-quarters
            s += __shfl_xor(s, 32);
            if (hs == 0) ls[w * 49 + i * 7 + j][ps] = s * 8.0f;  // * sqrt(64)
        }
    }
    __syncthreads();

    // ---- softmax over 196 (cooperative: 16 pixels x 16 chunks) ----
    {
        const int spx = tid >> 4;        // pixel 0..15
        const int ch  = tid & 15;        // chunk 0..15 (within-wave low bits)
        float v[13];
        float m = -INFINITY;
#pragma unroll
        for (int i = 0; i < 13; ++i) {
            v[i] = ls[ch + 16 * i][spx];
            m = fmaxf(m, v[i]);
        }
#pragma unroll
        for (int d = 1; d < 16; d <<= 1) m = fmaxf(m, __shfl_xor(m, d));
        float sum = 0.f;
#pragma unroll
        for (int i = 0; i < 13; ++i) { v[i] = __expf(v[i] - m); sum += v[i]; }
#pragma unroll
        for (int d = 1; d < 16; d <<= 1) sum += __shfl_xor(sum, d);
        const float inv = 1.0f / sum;
#pragma unroll
        for (int i = 0; i < 13; ++i) ls[ch + 16 * i][spx] = v[i] * inv;
    }
    __syncthreads();

    // ---- phase 2: y[h] = sum_k att[k] * g[t][h][key_pix] ----
    const float* gb = g_t + ((size_t)((b * TC + w) * NHEAD) + hs * 16) * HWPIX;
    float acc[16];
#pragma unroll
    for (int i = 0; i < 16; ++i) acc[i] = 0.f;
#pragma unroll
    for (int i = 0; i < 7; ++i) {
        const int nx = min(max(X - PAD + i, 0), HH - 1);
#pragma unroll
        for (int j = 0; j < 7; ++j) {
            const int ny = min(max(Y - PAD + j, 0), WW - 1);
            const int kp = nx * WW + ny;
            const float a = ls[w * 49 + i * 7 + j][ps];   // broadcast x4
#pragma unroll
            for (int hh = 0; hh < 16; ++hh)
                acc[hh] = fmaf(a, gb[(size_t)hh * HWPIX + kp], acc[hh]);
        }
    }
#pragma unroll
    for (int hh = 0; hh < 16; ++hh)
        y_lds[w][hs * 16 + hh][ps] = acc[hh];
    __syncthreads();

    // ---- reduce over t and store y_t (coalesced) ----
#pragma unroll
    for (int j = 0; j < 4; ++j) {
        const int idx = j * 256 + tid;           // 0..1023
        const int h   = idx >> 4;
        const int pp  = idx & 15;
        const float yv = y_lds[0][h][pp] + y_lds[1][h][pp]
                       + y_lds[2][h][pp] + y_lds[3][h][pp];
        y_t[((size_t)(b * NHEAD) + h) * HWPIX + p0 + pp] = yv;
    }
}

// ---------------------------------------------------------------------------
// K3: output projection + residual; y_t reads now coalesced per h.
// grid (18 pixtiles, 16 c-groups of 8). w_out wave-uniform scalar loads.
// ---------------------------------------------------------------------------
__global__ __launch_bounds__(256) void out_kernel(
    const float* __restrict__ x,
    const float* __restrict__ w_out,
    const float* __restrict__ y_t,
    float* __restrict__ out)
{
    const int p   = blockIdx.x * 256 + threadIdx.x;  // 0..4607
    const int c0  = blockIdx.y * 8;
    const int b   = p / HWPIX;
    const int rem = p % HWPIX;

    float acc[8];
#pragma unroll
    for (int j = 0; j < 8; ++j) acc[j] = 0.f;

    const float* yb = y_t + (size_t)b * NHEAD * HWPIX + rem;
#pragma unroll 8
    for (int h = 0; h < NHEAD; ++h) {
        const float yv = yb[(size_t)h * HWPIX];
#pragma unroll
        for (int j = 0; j < 8; ++j)
            acc[j] = fmaf(w_out[(size_t)(c0 + j) * NHEAD + h], yv, acc[j]);
    }

#pragma unroll
    for (int j = 0; j < 8; ++j) {
        const int c = c0 + j;
        const float xi = x[((size_t)(b * CCH + c) * TT) * HWPIX + rem];
        out[(size_t)(b * CCH + c) * HWPIX + rem] = xi + acc[j];
    }
}

// ---------------------------------------------------------------------------
extern "C" void kernel_launch(void* const* d_in, const int* in_sizes, int n_in,
                              void* d_out, int out_size, void* d_ws, size_t ws_size,
                              hipStream_t stream)
{
    const float* x       = (const float*)d_in[0];
    const float* w_theta = (const float*)d_in[1];
    const float* w_phi   = (const float*)d_in[2];
    const float* w_g     = (const float*)d_in[3];
    const float* w_out   = (const float*)d_in[4];
    float* out = (float*)d_out;

    float* ws    = (float*)d_ws;
    float* q_t   = ws;                                         // B*64*2304
    float* phi_t = q_t + (size_t)BATCH * NHEAD * HWPIX;        // B*4*64*2304
    float* g_t   = phi_t + (size_t)BATCH * TC * NHEAD * HWPIX;
    float* y_t   = q_t;   // alias: blocks read q only for their own pixels first

    dim3 g1(HWPIX / 256, 4, BATCH * TT);       // (9, 4, 10)
    proj_kernel<<<g1, 256, 0, stream>>>(x, w_theta, w_phi, w_g, q_t, phi_t, g_t);

    dim3 g2(HWPIX / 16, BATCH);                // (144, 2)
    attn_kernel<<<g2, 256, 0, stream>>>(phi_t, g_t, q_t, y_t);

    dim3 g3(BATCH * HWPIX / 256, CCH / 8);     // (18, 16)
    out_kernel<<<g3, 256, 0, stream>>>(x, w_out, y_t, out);
}